// Round 1
// baseline (514.942 us; speedup 1.0000x reference)
//
#include <hip/hip_runtime.h>
#include <stdint.h>

typedef __attribute__((ext_vector_type(4))) float f32x4;
typedef __attribute__((ext_vector_type(8))) __bf16 bf16x8;

__device__ __forceinline__ uint16_t f2bf(float f) {
  uint32_t u = __builtin_bit_cast(uint32_t, f);
  u += 0x7FFFu + ((u >> 16) & 1u);
  return (uint16_t)(u >> 16);
}

__device__ __forceinline__ void load_lds16(const uint16_t* g, uint16_t* l) {
  __builtin_amdgcn_global_load_lds((const __attribute__((address_space(1))) void*)g,
                                   (__attribute__((address_space(3))) void*)l, 16, 0, 0);
}

// ---------------- fp32 -> bf16 elementwise convert (4 elems/thread) ----------------
__global__ __launch_bounds__(256) void k_convert(const float* __restrict__ in,
                                                 uint16_t* __restrict__ out, int n4) {
  int i = blockIdx.x * blockDim.x + threadIdx.x;
  if (i < n4) {
    float4 v = ((const float4*)in)[i];
    union { uint16_t u[4]; uint64_t q; } o;
    o.u[0] = f2bf(v.x); o.u[1] = f2bf(v.y); o.u[2] = f2bf(v.z); o.u[3] = f2bf(v.w);
    ((uint64_t*)out)[i] = o.q;
  }
}

// ---------------- W[K][N] fp32 -> Wt[N][K] bf16 ----------------
__global__ __launch_bounds__(256) void k_transpose_w(const float* __restrict__ W,
                                                     uint16_t* __restrict__ Wt,
                                                     int K, int N) {
  __shared__ float tile[32][33];
  int n0 = blockIdx.x * 32, k0 = blockIdx.y * 32;
  int c = threadIdx.x & 31, r0 = threadIdx.x >> 5;
#pragma unroll
  for (int i = 0; i < 4; i++) {
    int r = r0 + i * 8;
    tile[r][c] = W[(size_t)(k0 + r) * N + n0 + c];
  }
  __syncthreads();
#pragma unroll
  for (int i = 0; i < 4; i++) {
    int r = r0 + i * 8;
    Wt[(size_t)(n0 + r) * K + k0 + c] = f2bf(tile[c][r]);
  }
}

// ---------------- V part of kv[b][l][2048] -> Vt[b*8+h][128][4096] bf16 ----------------
__global__ __launch_bounds__(256) void k_transpose_v(const uint16_t* __restrict__ kv,
                                                     uint16_t* __restrict__ vt) {
  __shared__ uint16_t tile[32][33];
  int bh = blockIdx.z, b = bh >> 3, h = bh & 7;
  int d0 = blockIdx.x * 32, l0 = blockIdx.y * 32;
  int c = threadIdx.x & 31, r0 = threadIdx.x >> 5;
#pragma unroll
  for (int i = 0; i < 4; i++) {
    int r = r0 + i * 8;
    tile[r][c] = kv[((size_t)(b * 4096 + l0 + r)) * 2048 + 1024 + h * 128 + d0 + c];
  }
  __syncthreads();
#pragma unroll
  for (int i = 0; i < 4; i++) {
    int r = r0 + i * 8;
    vt[((size_t)(bh * 128 + d0 + r)) * 4096 + l0 + c] = tile[c][r];
  }
}

// ---------------- GEMM: C[M][N] = A[M][K] * Bt[N][K]^T, bf16 in, fp32 acc ----------------
// m97 structure: 128x128 tile, BK=32, 4 waves of 4x4 16x16x32 MFMAs, global_load_lds w=16.
template <int F32OUT>
__global__ __launch_bounds__(256) void k_gemm_bt(const uint16_t* __restrict__ A,
                                                 const uint16_t* __restrict__ Bt,
                                                 uint16_t* __restrict__ Cb,
                                                 float* __restrict__ Cf,
                                                 const float* __restrict__ bias,
                                                 int M, int N, int K) {
  __shared__ uint16_t la[128 * 32];
  __shared__ uint16_t lb[128 * 32];
  const int tid = threadIdx.x;
  const int lane = tid & 63, w = tid >> 6;
  const int quad = lane >> 4, l16 = lane & 15;
  const int wr = (w >> 1) * 64, wc = (w & 1) * 64;
  const size_t tr0 = (size_t)blockIdx.y * 128, tc0 = (size_t)blockIdx.x * 128;
  f32x4 acc[4][4] = {};
  const int r0a = tid >> 2;               // chunk tid   : rows 0..63
  const int s0a = (tid & 3) * 8;          // seg within 32-k row
  const uint16_t* Ab = A + tr0 * K;
  const uint16_t* Bb = Bt + tc0 * K;
  for (int k0 = 0; k0 < K; k0 += 32) {
    __syncthreads();
    load_lds16(Ab + (size_t)r0a * K + k0 + s0a, la + tid * 8);
    load_lds16(Ab + (size_t)(r0a + 64) * K + k0 + s0a, la + (tid + 256) * 8);
    load_lds16(Bb + (size_t)r0a * K + k0 + s0a, lb + tid * 8);
    load_lds16(Bb + (size_t)(r0a + 64) * K + k0 + s0a, lb + (tid + 256) * 8);
    __syncthreads();
    bf16x8 af[4], bfr[4];
#pragma unroll
    for (int i = 0; i < 4; i++) af[i] = *(const bf16x8*)&la[(wr + i * 16 + l16) * 32 + quad * 8];
#pragma unroll
    for (int j = 0; j < 4; j++) bfr[j] = *(const bf16x8*)&lb[(wc + j * 16 + l16) * 32 + quad * 8];
#pragma unroll
    for (int i = 0; i < 4; i++)
#pragma unroll
      for (int j = 0; j < 4; j++)
        acc[i][j] = __builtin_amdgcn_mfma_f32_16x16x32_bf16(af[i], bfr[j], acc[i][j], 0, 0, 0);
  }
#pragma unroll
  for (int i = 0; i < 4; i++) {
#pragma unroll
    for (int j = 0; j < 4; j++) {
      size_t row = tr0 + wr + i * 16 + quad * 4;
      size_t col = tc0 + wc + j * 16 + l16;
#pragma unroll
      for (int r = 0; r < 4; r++) {
        if constexpr (F32OUT)
          Cf[(row + r) * N + col] = acc[i][j][r] + bias[col];
        else
          Cb[(row + r) * N + col] = f2bf(acc[i][j][r]);
      }
    }
  }
}

// ---------------- flash attention ----------------
// grid (16 qblocks, 8 heads, 2 batch), 256 thr. Wave w handles 16 query rows.
// Q frags live in registers; K/Vt chunks (64 keys) staged in padded LDS; P via
// per-wave LDS round-trip (C-layout -> A-layout).
__global__ __launch_bounds__(256) void k_attn(const uint16_t* __restrict__ q,
                                              const uint16_t* __restrict__ kv,
                                              const uint16_t* __restrict__ vt,
                                              const float* __restrict__ sims,
                                              const float* __restrict__ beta,
                                              uint16_t* __restrict__ outp) {
  __shared__ uint16_t Kl[64 * 136];   // [key][hd], pad 128->136
  __shared__ uint16_t Vl[128 * 72];   // [vcol][key], pad 64->72
  __shared__ uint16_t Pl[4][16 * 72]; // per wave [qrow][key], pad 64->72
  const int b = blockIdx.z, h = blockIdx.y, q0 = blockIdx.x * 64;
  const int tid = threadIdx.x, lane = tid & 63, w = tid >> 6;
  const int quad = lane >> 4, l16 = lane & 15;
  const float beta0 = beta[0];
  const float scale = 0.03125f; // 1024^-0.5

  bf16x8 qf[4];
  {
    const uint16_t* qrow = q + ((size_t)(b * 1024 + q0 + w * 16 + l16)) * 1024 + h * 128 + quad * 8;
#pragma unroll
    for (int ks = 0; ks < 4; ks++) qf[ks] = *(const bf16x8*)(qrow + ks * 32);
  }
  f32x4 o[8] = {};
  float mrow[4] = {-INFINITY, -INFINITY, -INFINITY, -INFINITY};
  float lrow[4] = {0.f, 0.f, 0.f, 0.f};

  for (int l0 = 0; l0 < 4096; l0 += 64) {
    __syncthreads(); // previous chunk's reads done before restage
    // stage K chunk: 64 rows x 128 hd (16B per op)
#pragma unroll
    for (int ii = 0; ii < 4; ii++) {
      int idx = tid + ii * 256;
      int row = idx >> 4, seg = (idx & 15) * 8;
      *(bf16x8*)&Kl[row * 136 + seg] =
          *(const bf16x8*)&kv[((size_t)(b * 4096 + l0 + row)) * 2048 + h * 128 + seg];
    }
    // stage Vt chunk: 128 rows x 64 keys
#pragma unroll
    for (int ii = 0; ii < 4; ii++) {
      int idx = tid + ii * 256;
      int row = idx >> 3, seg = (idx & 7) * 8;
      *(bf16x8*)&Vl[row * 72 + seg] =
          *(const bf16x8*)&vt[((size_t)((b * 8 + h) * 128 + row)) * 4096 + l0 + seg];
    }
    __syncthreads();
    // S = Q K^T  (4 col-frags of 16 keys, K-chain over hd)
    f32x4 s[4];
#pragma unroll
    for (int nb = 0; nb < 4; nb++) {
      f32x4 a = {};
#pragma unroll
      for (int ks = 0; ks < 4; ks++) {
        bf16x8 kf = *(const bf16x8*)&Kl[(nb * 16 + l16) * 136 + ks * 32 + quad * 8];
        a = __builtin_amdgcn_mfma_f32_16x16x32_bf16(qf[ks], kf, a, 0, 0, 0);
      }
      s[nb] = a;
    }
    const float simv = sims[b * 4 + (l0 >> 10)] * beta0;
#pragma unroll
    for (int nb = 0; nb < 4; nb++)
#pragma unroll
      for (int r = 0; r < 4; r++) s[nb][r] = s[nb][r] * scale + simv;
    // row max across 64 keys (4 frags x 16 lanes of the quad group)
    float alpha[4];
#pragma unroll
    for (int r = 0; r < 4; r++) {
      float m0 = fmaxf(fmaxf(s[0][r], s[1][r]), fmaxf(s[2][r], s[3][r]));
      m0 = fmaxf(m0, __shfl_xor(m0, 1));
      m0 = fmaxf(m0, __shfl_xor(m0, 2));
      m0 = fmaxf(m0, __shfl_xor(m0, 4));
      m0 = fmaxf(m0, __shfl_xor(m0, 8));
      float mn = fmaxf(mrow[r], m0);
      alpha[r] = __expf(mrow[r] - mn);
      mrow[r] = mn;
    }
    // p = exp(s - m), row-sum, spill P to LDS (C-layout write)
    float rs[4] = {0.f, 0.f, 0.f, 0.f};
#pragma unroll
    for (int nb = 0; nb < 4; nb++) {
#pragma unroll
      for (int r = 0; r < 4; r++) {
        float p = __expf(s[nb][r] - mrow[r]);
        rs[r] += p;
        Pl[w][(quad * 4 + r) * 72 + nb * 16 + l16] = f2bf(p);
      }
    }
#pragma unroll
    for (int r = 0; r < 4; r++) {
      float t = rs[r];
      t += __shfl_xor(t, 1);
      t += __shfl_xor(t, 2);
      t += __shfl_xor(t, 4);
      t += __shfl_xor(t, 8);
      lrow[r] = lrow[r] * alpha[r] + t;
    }
#pragma unroll
    for (int nb = 0; nb < 8; nb++)
#pragma unroll
      for (int r = 0; r < 4; r++) o[nb][r] *= alpha[r];
    __asm__ volatile("s_waitcnt lgkmcnt(0)" ::: "memory"); // wave-local P visibility
    // O += P V  (A-layout P read, Vt B-frags)
#pragma unroll
    for (int ks = 0; ks < 2; ks++) {
      bf16x8 pf = *(const bf16x8*)&Pl[w][l16 * 72 + ks * 32 + quad * 8];
#pragma unroll
      for (int nb = 0; nb < 8; nb++) {
        bf16x8 vf = *(const bf16x8*)&Vl[(nb * 16 + l16) * 72 + ks * 32 + quad * 8];
        o[nb] = __builtin_amdgcn_mfma_f32_16x16x32_bf16(pf, vf, o[nb], 0, 0, 0);
      }
    }
  }
  // epilogue: normalize and store [b][n][h*128+col] bf16
#pragma unroll
  for (int r = 0; r < 4; r++) {
    float inv = 1.0f / lrow[r];
    size_t row = (size_t)(b * 1024 + q0 + w * 16 + quad * 4 + r);
#pragma unroll
    for (int nb = 0; nb < 8; nb++)
      outp[row * 1024 + h * 128 + nb * 16 + l16] = f2bf(o[nb][r] * inv);
  }
}

// ---------------- launch ----------------
extern "C" void kernel_launch(void* const* d_in, const int* in_sizes, int n_in,
                              void* d_out, int out_size, void* d_ws, size_t ws_size,
                              hipStream_t stream) {
  (void)in_sizes; (void)n_in; (void)out_size; (void)ws_size;
  const float* x    = (const float*)d_in[0]; // [2,1024,1024]
  const float* ctx  = (const float*)d_in[1]; // [2,4,1024,1024]
  const float* sims = (const float*)d_in[2]; // [2,4]
  const float* Wq   = (const float*)d_in[3]; // [1024,1024]
  const float* Wkv  = (const float*)d_in[4]; // [1024,2048]
  const float* beta = (const float*)d_in[5]; // scalar
  const float* Wout = (const float*)d_in[6]; // [1024,1024]
  const float* bout = (const float*)d_in[7]; // [1024]
  float* out = (float*)d_out;                // [2,1024,1024] fp32

  char* ws = (char*)d_ws; // 84 MB used
  uint16_t* xb    = (uint16_t*)(ws + 0);          // 4 MB  [2048][1024]
  uint16_t* ctxb  = (uint16_t*)(ws + (4u << 20)); // 16 MB [8192][1024]
  uint16_t* wqt   = (uint16_t*)(ws + (20u << 20)); // 2 MB [1024][1024]
  uint16_t* wkvt  = (uint16_t*)(ws + (22u << 20)); // 4 MB [2048][1024]
  uint16_t* woutt = (uint16_t*)(ws + (26u << 20)); // 2 MB [1024][1024]
  uint16_t* qb    = (uint16_t*)(ws + (28u << 20)); // 4 MB [2048][1024]
  uint16_t* kvb   = (uint16_t*)(ws + (32u << 20)); // 32 MB [8192][2048]
  uint16_t* vtb   = (uint16_t*)(ws + (64u << 20)); // 16 MB [16][128][4096]
  uint16_t* attb  = (uint16_t*)(ws + (80u << 20)); // 4 MB [2048][1024]

  k_convert<<<2048, 256, 0, stream>>>(x, xb, 2 * 1024 * 1024 / 4);
  k_convert<<<8192, 256, 0, stream>>>(ctx, ctxb, 8 * 1024 * 1024 / 4);
  k_transpose_w<<<dim3(32, 32), 256, 0, stream>>>(Wq, wqt, 1024, 1024);
  k_transpose_w<<<dim3(64, 32), 256, 0, stream>>>(Wkv, wkvt, 1024, 2048);
  k_transpose_w<<<dim3(32, 32), 256, 0, stream>>>(Wout, woutt, 1024, 1024);
  // q = x @ Wq  -> bf16
  k_gemm_bt<0><<<dim3(8, 16), 256, 0, stream>>>(xb, wqt, qb, nullptr, nullptr, 2048, 1024, 1024);
  // kv = ctx @ Wkv -> bf16
  k_gemm_bt<0><<<dim3(16, 64), 256, 0, stream>>>(ctxb, wkvt, kvb, nullptr, nullptr, 8192, 2048, 1024);
  // Vt for attention
  k_transpose_v<<<dim3(4, 128, 16), 256, 0, stream>>>(kvb, vtb);
  // attention
  k_attn<<<dim3(16, 8, 2), 256, 0, stream>>>(qb, kvb, vtb, sims, beta, attb);
  // out = att @ Wout + bout -> fp32
  k_gemm_bt<1><<<dim3(8, 16), 256, 0, stream>>>(attb, woutt, nullptr, out, bout, 2048, 1024, 1024);
}

// Round 2
// 321.442 us; speedup vs baseline: 1.6020x; 1.6020x over previous
//
#include <hip/hip_runtime.h>
#include <stdint.h>

typedef __attribute__((ext_vector_type(4))) float f32x4;
typedef __attribute__((ext_vector_type(8))) __bf16 bf16x8;

__device__ __forceinline__ uint16_t f2bf(float f) {
  uint32_t u = __builtin_bit_cast(uint32_t, f);
  u += 0x7FFFu + ((u >> 16) & 1u);
  return (uint16_t)(u >> 16);
}

__device__ __forceinline__ float bf2f(uint16_t u) {
  uint32_t v = ((uint32_t)u) << 16;
  return __builtin_bit_cast(float, v);
}

__device__ __forceinline__ void load_lds16(const uint16_t* g, uint16_t* l) {
  __builtin_amdgcn_global_load_lds((const __attribute__((address_space(1))) void*)g,
                                   (__attribute__((address_space(3))) void*)l, 16, 0, 0);
}

// ---------------- fp32 -> bf16 elementwise convert (4 elems/thread) ----------------
__global__ __launch_bounds__(256) void k_convert(const float* __restrict__ in,
                                                 uint16_t* __restrict__ out, int n4) {
  int i = blockIdx.x * blockDim.x + threadIdx.x;
  if (i < n4) {
    float4 v = ((const float4*)in)[i];
    union { uint16_t u[4]; uint64_t q; } o;
    o.u[0] = f2bf(v.x); o.u[1] = f2bf(v.y); o.u[2] = f2bf(v.z); o.u[3] = f2bf(v.w);
    ((uint64_t*)out)[i] = o.q;
  }
}

// ---------------- W[K][N] fp32 -> Wt[N][K] bf16 ----------------
__global__ __launch_bounds__(256) void k_transpose_w(const float* __restrict__ W,
                                                     uint16_t* __restrict__ Wt,
                                                     int K, int N) {
  __shared__ float tile[32][33];
  int n0 = blockIdx.x * 32, k0 = blockIdx.y * 32;
  int c = threadIdx.x & 31, r0 = threadIdx.x >> 5;
#pragma unroll
  for (int i = 0; i < 4; i++) {
    int r = r0 + i * 8;
    tile[r][c] = W[(size_t)(k0 + r) * N + n0 + c];
  }
  __syncthreads();
#pragma unroll
  for (int i = 0; i < 4; i++) {
    int r = r0 + i * 8;
    Wt[(size_t)(n0 + r) * K + k0 + c] = f2bf(tile[c][r]);
  }
}

// ---------------- V part of kv[b][l][2048] -> Vt[b*8+h][128][4096] bf16 ----------------
__global__ __launch_bounds__(256) void k_transpose_v(const uint16_t* __restrict__ kv,
                                                     uint16_t* __restrict__ vt) {
  __shared__ uint16_t tile[32][33];
  int bh = blockIdx.z, b = bh >> 3, h = bh & 7;
  int d0 = blockIdx.x * 32, l0 = blockIdx.y * 32;
  int c = threadIdx.x & 31, r0 = threadIdx.x >> 5;
#pragma unroll
  for (int i = 0; i < 4; i++) {
    int r = r0 + i * 8;
    tile[r][c] = kv[((size_t)(b * 4096 + l0 + r)) * 2048 + 1024 + h * 128 + d0 + c];
  }
  __syncthreads();
#pragma unroll
  for (int i = 0; i < 4; i++) {
    int r = r0 + i * 8;
    vt[((size_t)(bh * 128 + d0 + r)) * 4096 + l0 + c] = tile[c][r];
  }
}

// ---------------- GEMM: C[M][N] = A[M][K] * Bt[N][K]^T, bf16 in, fp32 acc ----------------
template <int F32OUT>
__global__ __launch_bounds__(256) void k_gemm_bt(const uint16_t* __restrict__ A,
                                                 const uint16_t* __restrict__ Bt,
                                                 uint16_t* __restrict__ Cb,
                                                 float* __restrict__ Cf,
                                                 const float* __restrict__ bias,
                                                 int M, int N, int K) {
  __shared__ uint16_t la[128 * 32];
  __shared__ uint16_t lb[128 * 32];
  const int tid = threadIdx.x;
  const int lane = tid & 63, w = tid >> 6;
  const int quad = lane >> 4, l16 = lane & 15;
  const int wr = (w >> 1) * 64, wc = (w & 1) * 64;
  const size_t tr0 = (size_t)blockIdx.y * 128, tc0 = (size_t)blockIdx.x * 128;
  f32x4 acc[4][4] = {};
  const int r0a = tid >> 2;
  const int s0a = (tid & 3) * 8;
  const uint16_t* Ab = A + tr0 * K;
  const uint16_t* Bb = Bt + tc0 * K;
  for (int k0 = 0; k0 < K; k0 += 32) {
    __syncthreads();
    load_lds16(Ab + (size_t)r0a * K + k0 + s0a, la + tid * 8);
    load_lds16(Ab + (size_t)(r0a + 64) * K + k0 + s0a, la + (tid + 256) * 8);
    load_lds16(Bb + (size_t)r0a * K + k0 + s0a, lb + tid * 8);
    load_lds16(Bb + (size_t)(r0a + 64) * K + k0 + s0a, lb + (tid + 256) * 8);
    __syncthreads();
    bf16x8 af[4], bfr[4];
#pragma unroll
    for (int i = 0; i < 4; i++) af[i] = *(const bf16x8*)&la[(wr + i * 16 + l16) * 32 + quad * 8];
#pragma unroll
    for (int j = 0; j < 4; j++) bfr[j] = *(const bf16x8*)&lb[(wc + j * 16 + l16) * 32 + quad * 8];
#pragma unroll
    for (int i = 0; i < 4; i++)
#pragma unroll
      for (int j = 0; j < 4; j++)
        acc[i][j] = __builtin_amdgcn_mfma_f32_16x16x32_bf16(af[i], bfr[j], acc[i][j], 0, 0, 0);
  }
#pragma unroll
  for (int i = 0; i < 4; i++) {
#pragma unroll
    for (int j = 0; j < 4; j++) {
      size_t row = tr0 + wr + i * 16 + quad * 4;
      size_t col = tc0 + wc + j * 16 + l16;
#pragma unroll
      for (int r = 0; r < 4; r++) {
        if constexpr (F32OUT)
          Cf[(row + r) * N + col] = acc[i][j][r] + bias[col];
        else
          Cb[(row + r) * N + col] = f2bf(acc[i][j][r]);
      }
    }
  }
}

// ---------------- flash attention, key-split x4 (flash-decoding style) ----------------
// grid (16 qblocks, 8 heads, 8 = b*4+split), 256 thr. Wave w handles 16 query rows,
// each block handles 1024 keys (= one doc, so sim bias is a block constant).
// P scratch is ALIASED into Kl: a third __syncthreads separates the last Kl
// B-frag read from the P write; P reads are wave-local and precede the loop-top
// barrier of the next iteration. LDS total 35840 B -> 4 blocks/CU.
__global__ __launch_bounds__(256) void k_attn(const uint16_t* __restrict__ q,
                                              const uint16_t* __restrict__ kv,
                                              const uint16_t* __restrict__ vt,
                                              const float* __restrict__ sims,
                                              const float* __restrict__ beta,
                                              uint16_t* __restrict__ po,
                                              float* __restrict__ pm,
                                              float* __restrict__ pl) {
  __shared__ uint16_t Kl[64 * 136];   // [key][hd], pad 128->136; P scratch aliased here
  __shared__ uint16_t Vl[128 * 72];   // [vcol][key], pad 64->72
  const int bz = blockIdx.z, b = bz >> 2, sp = bz & 3;
  const int h = blockIdx.y, q0 = blockIdx.x * 64;
  const int tid = threadIdx.x, lane = tid & 63, w = tid >> 6;
  const int quad = lane >> 4, l16 = lane & 15;
  const float scale = 0.03125f; // 1024^-0.5
  const float simv = sims[b * 4 + sp] * beta[0];
  uint16_t* Pw = Kl + w * 1152;       // per-wave 16 rows x 72 (aliased into Kl)

  bf16x8 qf[4];
  {
    const uint16_t* qrow = q + ((size_t)(b * 1024 + q0 + w * 16 + l16)) * 1024 + h * 128 + quad * 8;
#pragma unroll
    for (int ks = 0; ks < 4; ks++) qf[ks] = *(const bf16x8*)(qrow + ks * 32);
  }
  f32x4 o[8] = {};
  float mrow[4] = {-INFINITY, -INFINITY, -INFINITY, -INFINITY};
  float lrow[4] = {0.f, 0.f, 0.f, 0.f};

  for (int c = 0; c < 16; c++) {
    const int l0 = sp * 1024 + c * 64;
    __syncthreads(); // prev chunk's P/V reads done before restage
    // stage K chunk: 64 rows x 128 hd
#pragma unroll
    for (int ii = 0; ii < 4; ii++) {
      int idx = tid + ii * 256;
      int row = idx >> 4, seg = (idx & 15) * 8;
      *(bf16x8*)&Kl[row * 136 + seg] =
          *(const bf16x8*)&kv[((size_t)(b * 4096 + l0 + row)) * 2048 + h * 128 + seg];
    }
    // stage Vt chunk: 128 rows x 64 keys
#pragma unroll
    for (int ii = 0; ii < 4; ii++) {
      int idx = tid + ii * 256;
      int row = idx >> 3, seg = (idx & 7) * 8;
      *(bf16x8*)&Vl[row * 72 + seg] =
          *(const bf16x8*)&vt[((size_t)((b * 8 + h) * 128 + row)) * 4096 + l0 + seg];
    }
    __syncthreads();
    // S = Q K^T
    f32x4 s[4];
#pragma unroll
    for (int nb = 0; nb < 4; nb++) {
      f32x4 a = {};
#pragma unroll
      for (int ks = 0; ks < 4; ks++) {
        bf16x8 kf = *(const bf16x8*)&Kl[(nb * 16 + l16) * 136 + ks * 32 + quad * 8];
        a = __builtin_amdgcn_mfma_f32_16x16x32_bf16(qf[ks], kf, a, 0, 0, 0);
      }
      s[nb] = a;
    }
#pragma unroll
    for (int nb = 0; nb < 4; nb++)
#pragma unroll
      for (int r = 0; r < 4; r++) s[nb][r] = s[nb][r] * scale + simv;
    // online softmax: row max across 64 keys
    float alpha[4];
#pragma unroll
    for (int r = 0; r < 4; r++) {
      float m0 = fmaxf(fmaxf(s[0][r], s[1][r]), fmaxf(s[2][r], s[3][r]));
      m0 = fmaxf(m0, __shfl_xor(m0, 1));
      m0 = fmaxf(m0, __shfl_xor(m0, 2));
      m0 = fmaxf(m0, __shfl_xor(m0, 4));
      m0 = fmaxf(m0, __shfl_xor(m0, 8));
      float mn = fmaxf(mrow[r], m0);
      alpha[r] = __expf(mrow[r] - mn);
      mrow[r] = mn;
    }
    float p_val[4][4];
    float rs[4] = {0.f, 0.f, 0.f, 0.f};
#pragma unroll
    for (int nb = 0; nb < 4; nb++)
#pragma unroll
      for (int r = 0; r < 4; r++) {
        float p = __expf(s[nb][r] - mrow[r]);
        p_val[nb][r] = p;
        rs[r] += p;
      }
#pragma unroll
    for (int r = 0; r < 4; r++) {
      float t = rs[r];
      t += __shfl_xor(t, 1);
      t += __shfl_xor(t, 2);
      t += __shfl_xor(t, 4);
      t += __shfl_xor(t, 8);
      lrow[r] = lrow[r] * alpha[r] + t;
    }
#pragma unroll
    for (int nb = 0; nb < 8; nb++)
#pragma unroll
      for (int r = 0; r < 4; r++) o[nb][r] *= alpha[r];
    __syncthreads(); // all waves done reading Kl as K before P overwrites it
#pragma unroll
    for (int nb = 0; nb < 4; nb++)
#pragma unroll
      for (int r = 0; r < 4; r++)
        Pw[(quad * 4 + r) * 72 + nb * 16 + l16] = f2bf(p_val[nb][r]);
    __asm__ volatile("s_waitcnt lgkmcnt(0)" ::: "memory"); // wave-local P visibility
    // O += P V
#pragma unroll
    for (int ks = 0; ks < 2; ks++) {
      bf16x8 pf = *(const bf16x8*)&Pw[l16 * 72 + ks * 32 + quad * 8];
#pragma unroll
      for (int nb = 0; nb < 8; nb++) {
        bf16x8 vf = *(const bf16x8*)&Vl[(nb * 16 + l16) * 72 + ks * 32 + quad * 8];
        o[nb] = __builtin_amdgcn_mfma_f32_16x16x32_bf16(pf, vf, o[nb], 0, 0, 0);
      }
    }
  }
  // epilogue: store unnormalized partial O (bf16) + m,l per row
  const int rowbase = (sp * 16 + b * 8 + h) * 1024 + q0 + w * 16;
#pragma unroll
  for (int r = 0; r < 4; r++) {
    int row = rowbase + quad * 4 + r;
#pragma unroll
    for (int nb = 0; nb < 8; nb++)
      po[(size_t)row * 128 + nb * 16 + l16] = f2bf(o[nb][r]);
    if (l16 == 0) {
      pm[row] = mrow[r];
      pl[row] = lrow[r];
    }
  }
}

// ---------------- merge 4 key-split partials -> attb[b][q][h*128+d] bf16 ----------------
__global__ __launch_bounds__(256) void k_merge(const uint16_t* __restrict__ po,
                                               const float* __restrict__ pm,
                                               const float* __restrict__ pl,
                                               uint16_t* __restrict__ attb) {
  const int bq = blockIdx.x;           // b*1024 + q
  const int b = bq >> 10, qi = bq & 1023;
  const int t = threadIdx.x;
  const int h = t >> 5, d0 = (t & 31) * 4;
  const int bh = b * 8 + h;
  float m[4];
  float M = -INFINITY;
#pragma unroll
  for (int s = 0; s < 4; s++) {
    m[s] = pm[(s * 16 + bh) * 1024 + qi];
    M = fmaxf(M, m[s]);
  }
  float den = 0.f, wgt[4];
#pragma unroll
  for (int s = 0; s < 4; s++) {
    wgt[s] = __expf(m[s] - M);
    den += wgt[s] * pl[(s * 16 + bh) * 1024 + qi];
  }
  const float inv = 1.0f / den;
  float acc[4] = {0.f, 0.f, 0.f, 0.f};
#pragma unroll
  for (int s = 0; s < 4; s++) {
    const uint16_t* p = &po[(((size_t)(s * 16 + bh)) * 1024 + qi) * 128 + d0];
    union { uint64_t q; uint16_t u[4]; } v;
    v.q = *(const uint64_t*)p;
#pragma unroll
    for (int j = 0; j < 4; j++) acc[j] += wgt[s] * bf2f(v.u[j]);
  }
  union { uint64_t q; uint16_t u[4]; } o;
#pragma unroll
  for (int j = 0; j < 4; j++) o.u[j] = f2bf(acc[j] * inv);
  *(uint64_t*)&attb[((size_t)(b * 1024 + qi)) * 1024 + h * 128 + d0] = o.q;
}

// ---------------- launch ----------------
extern "C" void kernel_launch(void* const* d_in, const int* in_sizes, int n_in,
                              void* d_out, int out_size, void* d_ws, size_t ws_size,
                              hipStream_t stream) {
  (void)in_sizes; (void)n_in; (void)out_size; (void)ws_size;
  const float* x    = (const float*)d_in[0]; // [2,1024,1024]
  const float* ctx  = (const float*)d_in[1]; // [2,4,1024,1024]
  const float* sims = (const float*)d_in[2]; // [2,4]
  const float* Wq   = (const float*)d_in[3]; // [1024,1024]
  const float* Wkv  = (const float*)d_in[4]; // [1024,2048]
  const float* beta = (const float*)d_in[5]; // scalar
  const float* Wout = (const float*)d_in[6]; // [1024,1024]
  const float* bout = (const float*)d_in[7]; // [1024]
  float* out = (float*)d_out;                // [2,1024,1024] fp32

  char* ws = (char*)d_ws; // 84 MB used
  uint16_t* xb    = (uint16_t*)(ws + 0);           // 4 MB  [2048][1024]   (dead after q GEMM)
  uint16_t* ctxb  = (uint16_t*)(ws + (4u << 20));  // 16 MB [8192][1024]   (dead after kv GEMM)
  uint16_t* wqt   = (uint16_t*)(ws + (20u << 20)); // 2 MB
  uint16_t* wkvt  = (uint16_t*)(ws + (22u << 20)); // 4 MB
  uint16_t* woutt = (uint16_t*)(ws + (26u << 20)); // 2 MB (needed at end)
  uint16_t* qb    = (uint16_t*)(ws + (28u << 20)); // 4 MB
  uint16_t* kvb   = (uint16_t*)(ws + (32u << 20)); // 32 MB
  uint16_t* vtb   = (uint16_t*)(ws + (64u << 20)); // 16 MB
  uint16_t* attb  = (uint16_t*)(ws + (80u << 20)); // 4 MB
  // key-split partials reuse the xb/ctxb region (0..20 MB), dead by attention time
  uint16_t* po = (uint16_t*)(ws + 0);              // 16 MB [4][16][1024][128] bf16
  float*    pm = (float*)(ws + (16u << 20));       // 256 KB [4][16][1024]
  float*    pl = (float*)(ws + (16u << 20) + (256u << 10)); // 256 KB

  k_convert<<<2048, 256, 0, stream>>>(x, xb, 2 * 1024 * 1024 / 4);
  k_convert<<<8192, 256, 0, stream>>>(ctx, ctxb, 8 * 1024 * 1024 / 4);
  k_transpose_w<<<dim3(32, 32), 256, 0, stream>>>(Wq, wqt, 1024, 1024);
  k_transpose_w<<<dim3(64, 32), 256, 0, stream>>>(Wkv, wkvt, 1024, 2048);
  k_transpose_w<<<dim3(32, 32), 256, 0, stream>>>(Wout, woutt, 1024, 1024);
  // q = x @ Wq -> bf16
  k_gemm_bt<0><<<dim3(8, 16), 256, 0, stream>>>(xb, wqt, qb, nullptr, nullptr, 2048, 1024, 1024);
  // kv = ctx @ Wkv -> bf16
  k_gemm_bt<0><<<dim3(16, 64), 256, 0, stream>>>(ctxb, wkvt, kvb, nullptr, nullptr, 8192, 2048, 1024);
  // Vt for attention
  k_transpose_v<<<dim3(4, 128, 16), 256, 0, stream>>>(kvb, vtb);
  // attention, key-split x4
  k_attn<<<dim3(16, 8, 8), 256, 0, stream>>>(qb, kvb, vtb, sims, beta, po, pm, pl);
  // merge partials
  k_merge<<<2048, 256, 0, stream>>>(po, pm, pl, attb);
  // out = att @ Wout + bout -> fp32
  k_gemm_bt<1><<<dim3(8, 16), 256, 0, stream>>>(attb, woutt, nullptr, out, bout, 2048, 1024, 1024);
}